// Round 1
// baseline (2525.775 us; speedup 1.0000x reference)
//
#include <hip/hip_runtime.h>
#include <cstdint>
#include <cstddef>

#define H 128
#define C 64
#define KITER 10

// ---------------- setup kernels ----------------

__global__ void k_zero(int* __restrict__ deg, double* __restrict__ stats, int n, int nstats) {
    int i = blockIdx.x * blockDim.x + threadIdx.x;
    if (i < n) deg[i] = 0;
    if (i < nstats) stats[i] = 0.0;
}

__global__ void k_degcount(const int* __restrict__ dst, int* __restrict__ deg, int E) {
    int e = blockIdx.x * blockDim.x + threadIdx.x;
    if (e < E) atomicAdd(&deg[dst[e]], 1);
}

// single block, 1024 threads: exclusive scan of deg -> row_ptr, row_cur
__global__ void k_scan(const int* __restrict__ deg, int* __restrict__ row_ptr,
                       int* __restrict__ row_cur, int n) {
    __shared__ int sums[1024];
    int t = threadIdx.x;
    int chunk = (n + 1023) / 1024;
    int lo = t * chunk;
    int hi = lo + chunk; if (hi > n) hi = n;
    int s = 0;
    for (int i = lo; i < hi; ++i) s += deg[i];
    sums[t] = s;
    __syncthreads();
    for (int off = 1; off < 1024; off <<= 1) {
        int v = (t >= off) ? sums[t - off] : 0;
        __syncthreads();
        sums[t] += v;
        __syncthreads();
    }
    int excl = sums[t] - s;
    int base = excl;
    for (int i = lo; i < hi; ++i) {
        row_ptr[i] = base;
        row_cur[i] = base;
        base += deg[i];
    }
    if (t == 1023) row_ptr[n] = sums[1023];
}

__global__ void k_norm(const int* __restrict__ deg, float* __restrict__ degc,
                       float* __restrict__ nrm, int n) {
    int i = blockIdx.x * blockDim.x + threadIdx.x;
    if (i < n) {
        int d = deg[i];
        float dc = (float)(d > 1 ? d : 1);
        degc[i] = dc;
        // correctly-rounded f32 of dc^-0.5 (matches np powf(x,-0.5))
        nrm[i] = (float)(1.0 / sqrt((double)dc));
    }
}

__global__ void k_scatter(const int* __restrict__ src, const int* __restrict__ dst,
                          int* __restrict__ row_cur, int* __restrict__ csr_src, int E) {
    int e = blockIdx.x * blockDim.x + threadIdx.x;
    if (e < E) {
        int d = dst[e];
        int pos = atomicAdd(&row_cur[d], 1);
        csr_src[pos] = src[e];
    }
}

// ---------------- per-iteration kernels ----------------

// lidx==0: argmax over input logits. one wave per node, lane = class.
__global__ __launch_bounds__(256) void k_pred0(const float* __restrict__ logits,
                                               int* __restrict__ pred, int n) {
    int wid = (blockIdx.x * blockDim.x + threadIdx.x) >> 6;
    int lane = threadIdx.x & 63;
    if (wid >= n) return;
    float v = logits[(size_t)wid * C + lane];
    int idx = lane;
    #pragma unroll
    for (int off = 1; off < 64; off <<= 1) {
        float ov = __shfl_xor(v, off);
        int oi = __shfl_xor(idx, off);
        // max with first-index tie-break (associative+commutative)
        if (ov > v || (ov == v && oi < idx)) { v = ov; idx = oi; }
    }
    if (lane == 0) pred[wid] = idx;
}

// lidx>0: thread-per-node fused featn = feat*norm, logits = featn@w + b, pred = argmax.
// Full featn row lives in 128 VGPRs; w reads are wave-uniform -> s_load.
// Sequential-h FMA accumulation per output (BLAS-like order).
__global__ __launch_bounds__(256) void k_predG(const float* __restrict__ feat,
                                               const float* __restrict__ nrm,
                                               const float* __restrict__ w_y,
                                               const float* __restrict__ b_y,
                                               int* __restrict__ pred, int n) {
    int node = blockIdx.x * blockDim.x + threadIdx.x;
    bool act = node < n;
    int ld = act ? node : 0;
    float nn = act ? nrm[ld] : 0.f;
    const float4* p4 = (const float4*)(feat + (size_t)ld * H);
    float fv[H];
    #pragma unroll
    for (int q = 0; q < H / 4; ++q) {
        float4 t = p4[q];
        fv[q * 4 + 0] = t.x * nn;
        fv[q * 4 + 1] = t.y * nn;
        fv[q * 4 + 2] = t.z * nn;
        fv[q * 4 + 3] = t.w * nn;
    }
    float best = -3.402823466e+38f;
    int bi = 0;
    for (int cb = 0; cb < C / 8; ++cb) {
        float acc[8];
        #pragma unroll
        for (int u = 0; u < 8; ++u) acc[u] = 0.f;
        const float* wp = w_y + cb * 8;
        #pragma unroll
        for (int h = 0; h < H; ++h) {
            #pragma unroll
            for (int u = 0; u < 8; ++u)
                acc[u] = fmaf(fv[h], wp[h * C + u], acc[u]);
        }
        #pragma unroll
        for (int u = 0; u < 8; ++u) {
            float val = acc[u] + b_y[cb * 8 + u];
            int c = cb * 8 + u;
            if (val > best) { best = val; bi = c; }  // strict > keeps first index
        }
    }
    if (act) pred[node] = bi;
}

// f1 (agreement fraction), f2 (neighborhood-histogram entropy), + LN stat sums.
__global__ __launch_bounds__(256) void k_edge(const int* __restrict__ row_ptr,
                                              const int* __restrict__ csr_src,
                                              const int* __restrict__ pred,
                                              const float* __restrict__ degc,
                                              float* __restrict__ f1, float* __restrict__ f2,
                                              double* __restrict__ stats_iter, int n) {
    __shared__ unsigned char hist[256][64];
    __shared__ double red[256];
    int t = threadIdx.x;
    int node = blockIdx.x * 256 + t;
    uint32_t* hp = (uint32_t*)hist[t];
    #pragma unroll
    for (int q = 0; q < 16; ++q) hp[q] = 0u;
    float v1 = 0.f, v2 = 0.f;
    bool act = node < n;
    if (act) {
        int lo = row_ptr[node], hi = row_ptr[node + 1];
        int pc = pred[node];
        int eq = 0;
        for (int j = lo; j < hi; ++j) {
            int p = pred[csr_src[j]];
            eq += (p == pc) ? 1 : 0;
            hist[t][p] += 1;
        }
        float dc = degc[node];
        v1 = (float)eq / dc;
        float s = 0.f;
        #pragma unroll
        for (int c = 0; c < 64; ++c) {
            float cv = (float)hist[t][c] / dc;
            cv = fmaxf(cv, 1e-5f);
            s += cv * logf(cv);
        }
        v2 = -s;
        f1[node] = v1;
        f2[node] = v2;
    }
    // block-reduce 4 sums (f64) then one atomic each
    double vals[4];
    vals[0] = act ? (double)v1 : 0.0;
    vals[1] = act ? (double)v1 * (double)v1 : 0.0;
    vals[2] = act ? (double)v2 : 0.0;
    vals[3] = act ? (double)v2 * (double)v2 : 0.0;
    for (int q = 0; q < 4; ++q) {
        red[t] = vals[q];
        __syncthreads();
        for (int off = 128; off >= 1; off >>= 1) {
            if (t < off) red[t] += red[t + off];
            __syncthreads();
        }
        if (t == 0) atomicAdd(&stats_iter[q], red[0]);
        __syncthreads();
    }
}

// SpMM + z + residual update. One wave per node; lane covers 2 feature dims.
__global__ __launch_bounds__(256) void k_spmm(const float* __restrict__ cur,
                                              float* __restrict__ nxt,
                                              const float* __restrict__ nrm,
                                              const int* __restrict__ row_ptr,
                                              const int* __restrict__ csr_src,
                                              const float* __restrict__ f1,
                                              const float* __restrict__ f2,
                                              const double* __restrict__ stats_iter,
                                              const float* __restrict__ tau1,
                                              const float* __restrict__ tau2,
                                              int n, double dN) {
    int wid = (blockIdx.x * blockDim.x + threadIdx.x) >> 6;
    int lane = threadIdx.x & 63;
    if (wid >= n) return;
    int node = __builtin_amdgcn_readfirstlane(wid);

    // z from global-LN(f1), LN(f2) stats
    double S1 = stats_iter[0], Q1 = stats_iter[1];
    double S2 = stats_iter[2], Q2 = stats_iter[3];
    double m1 = S1 / dN, m2 = S2 / dN;
    double var1 = Q1 / dN - m1 * m1;
    double var2 = Q2 / dN - m2 * m2;
    double rs1 = 1.0 / sqrt(var1 + 1e-5);
    double rs2 = 1.0 / sqrt(var2 + 1e-5);
    float ln1 = (float)(((double)f1[node] - m1) * rs1);
    float ln2 = (float)(((double)f2[node] - m2) * rs2);
    float z1 = 1.f / (1.f + expf(ln1 - tau1[0]));  // sigmoid(-(ln1 - tau1))
    float z2 = 1.f / (1.f + expf(ln2 - tau2[0]));
    float z = z1 * z2;

    float nr = nrm[node];
    int lo = row_ptr[node], hi = row_ptr[node + 1];
    float ax = 0.f, ay = 0.f;
    const float* basep = cur + (size_t)lane * 2;
    int j = lo;
    for (; j + 1 < hi; j += 2) {
        int s0 = csr_src[j];
        int s1 = csr_src[j + 1];
        float n0 = nrm[s0];
        float n1 = nrm[s1];
        const float2 v0 = *(const float2*)(basep + (size_t)s0 * H);
        const float2 v1 = *(const float2*)(basep + (size_t)s1 * H);
        ax = fmaf(v0.x, n0, ax); ay = fmaf(v0.y, n0, ay);
        ax = fmaf(v1.x, n1, ax); ay = fmaf(v1.y, n1, ay);
    }
    if (j < hi) {
        int s0 = csr_src[j];
        float n0 = nrm[s0];
        const float2 v0 = *(const float2*)(basep + (size_t)s0 * H);
        ax = fmaf(v0.x, n0, ax); ay = fmaf(v0.y, n0, ay);
    }
    const float2 own = *(const float2*)(cur + (size_t)node * H + lane * 2);
    float2 o;
    o.x = z * (ax * nr) + own.x * nr;
    o.y = z * (ay * nr) + own.y * nr;
    *(float2*)(nxt + (size_t)node * H + lane * 2) = o;
}

// ---------------- host ----------------

extern "C" void kernel_launch(void* const* d_in, const int* in_sizes, int n_in,
                              void* d_out, int out_size, void* d_ws, size_t ws_size,
                              hipStream_t stream) {
    const float* feat   = (const float*)d_in[0];
    const float* logits = (const float*)d_in[1];
    const float* w_y    = (const float*)d_in[2];
    const float* b_y    = (const float*)d_in[3];
    const float* tau1   = (const float*)d_in[4];
    const float* tau2   = (const float*)d_in[5];
    const int*   src    = (const int*)d_in[6];
    const int*   dst    = (const int*)d_in[7];
    // d_in[8] = k (always 10 per problem spec; cannot sync-read device scalar in capture)

    const int N = in_sizes[0] / H;
    const int E = in_sizes[6];
    float* out = (float*)d_out;

    char* ws = (char*)d_ws;
    size_t off = 0;
    auto carve = [&](size_t bytes) -> char* {
        char* p = ws + off;
        off = (off + bytes + 255) & ~(size_t)255;
        return p;
    };
    float*  featB   = (float*)carve((size_t)N * H * sizeof(float));
    float*  nrm     = (float*)carve((size_t)N * sizeof(float));
    float*  degc    = (float*)carve((size_t)N * sizeof(float));
    int*    pred    = (int*)  carve((size_t)N * sizeof(int));
    float*  f1      = (float*)carve((size_t)N * sizeof(float));
    float*  f2      = (float*)carve((size_t)N * sizeof(float));
    int*    deg     = (int*)  carve((size_t)N * sizeof(int));
    int*    row_ptr = (int*)  carve((size_t)(N + 1) * sizeof(int));
    int*    row_cur = (int*)  carve((size_t)N * sizeof(int));
    int*    csr_src = (int*)  carve((size_t)E * sizeof(int));
    double* stats   = (double*)carve((size_t)KITER * 8 * sizeof(double));

    const int TB = 256;
    int gN = (N + TB - 1) / TB;
    int gE = (E + TB - 1) / TB;

    k_zero<<<gN, TB, 0, stream>>>(deg, stats, N, KITER * 8);
    k_degcount<<<gE, TB, 0, stream>>>(dst, deg, E);
    k_scan<<<1, 1024, 0, stream>>>(deg, row_ptr, row_cur, N);
    k_norm<<<gN, TB, 0, stream>>>(deg, degc, nrm, N);
    k_scatter<<<gE, TB, 0, stream>>>(src, dst, row_cur, csr_src, E);

    const float* cur = feat;
    int gWave = (N + 3) / 4;  // wave-per-node kernels: 4 nodes / 256-thread block
    for (int l = 0; l < KITER; ++l) {
        float* nxt = (l % 2 == 0) ? featB : out;  // l=9 (odd) writes d_out
        if (l == 0)
            k_pred0<<<gWave, TB, 0, stream>>>(logits, pred, N);
        else
            k_predG<<<gN, TB, 0, stream>>>(cur, nrm, w_y, b_y, pred, N);
        k_edge<<<gN, TB, 0, stream>>>(row_ptr, csr_src, pred, degc, f1, f2,
                                      stats + (size_t)l * 8, N);
        k_spmm<<<gWave, TB, 0, stream>>>(cur, nxt, nrm, row_ptr, csr_src, f1, f2,
                                         stats + (size_t)l * 8, tau1, tau2, N, (double)N);
        cur = nxt;
    }
}

// Round 2
// 2293.101 us; speedup vs baseline: 1.1015x; 1.1015x over previous
//
#include <hip/hip_runtime.h>
#include <cstdint>
#include <cstddef>

#define H 128
#define C 64
#define KITER 10

// ---------------- setup kernels ----------------

__global__ void k_zero(int* __restrict__ deg, double* __restrict__ stats, int n, int nstats) {
    int i = blockIdx.x * blockDim.x + threadIdx.x;
    if (i < n) deg[i] = 0;
    if (i < nstats) stats[i] = 0.0;
}

__global__ void k_degcount(const int* __restrict__ dst, int* __restrict__ deg, int E) {
    int e = blockIdx.x * blockDim.x + threadIdx.x;
    if (e < E) atomicAdd(&deg[dst[e]], 1);
}

// ---- multi-block exclusive scan of deg -> row_ptr/row_cur (3 kernels) ----

__global__ __launch_bounds__(256) void k_blocksum(const int* __restrict__ deg,
                                                  int* __restrict__ bsum, int n) {
    __shared__ int red[256];
    int t = threadIdx.x;
    int i = blockIdx.x * 256 + t;
    red[t] = (i < n) ? deg[i] : 0;
    __syncthreads();
    for (int off = 128; off >= 1; off >>= 1) {
        if (t < off) red[t] += red[t + off];
        __syncthreads();
    }
    if (t == 0) bsum[blockIdx.x] = red[0];
}

// single block of 512 threads scans nb (<=512) partial sums -> exclusive boff;
// also writes row_ptr[n] = total.
__global__ __launch_bounds__(512) void k_scanb(const int* __restrict__ bsum,
                                               int* __restrict__ boff,
                                               int* __restrict__ row_ptr, int nb, int n) {
    __shared__ int s[512];
    int t = threadIdx.x;
    int v = (t < nb) ? bsum[t] : 0;
    s[t] = v;
    __syncthreads();
    for (int off = 1; off < 512; off <<= 1) {
        int u = (t >= off) ? s[t - off] : 0;
        __syncthreads();
        s[t] += u;
        __syncthreads();
    }
    if (t < nb) boff[t] = s[t] - v;  // exclusive
    if (t == 511) row_ptr[n] = s[511];
}

__global__ __launch_bounds__(256) void k_fill(const int* __restrict__ deg,
                                              const int* __restrict__ boff,
                                              int* __restrict__ row_ptr,
                                              int* __restrict__ row_cur, int n) {
    __shared__ int s[256];
    int t = threadIdx.x;
    int i = blockIdx.x * 256 + t;
    int d = (i < n) ? deg[i] : 0;
    s[t] = d;
    __syncthreads();
    for (int off = 1; off < 256; off <<= 1) {
        int u = (t >= off) ? s[t - off] : 0;
        __syncthreads();
        s[t] += u;
        __syncthreads();
    }
    if (i < n) {
        int base = boff[blockIdx.x] + s[t] - d;
        row_ptr[i] = base;
        row_cur[i] = base;
    }
}

__global__ void k_norm(const int* __restrict__ deg, float* __restrict__ degc,
                       float* __restrict__ nrm, int n) {
    int i = blockIdx.x * blockDim.x + threadIdx.x;
    if (i < n) {
        int d = deg[i];
        float dc = (float)(d > 1 ? d : 1);
        degc[i] = dc;
        nrm[i] = (float)(1.0 / sqrt((double)dc));  // correctly-rounded dc^-0.5
    }
}

__global__ void k_scatter(const int* __restrict__ src, const int* __restrict__ dst,
                          int* __restrict__ row_cur, int* __restrict__ csr_src, int E) {
    int e = blockIdx.x * blockDim.x + threadIdx.x;
    if (e < E) {
        int d = dst[e];
        int pos = atomicAdd(&row_cur[d], 1);
        csr_src[pos] = src[e];
    }
}

// featn0 = feat * norm (thread per float4)
__global__ __launch_bounds__(256) void k_scale(const float* __restrict__ feat,
                                               const float* __restrict__ nrm,
                                               float* __restrict__ featn, int n4) {
    int i = blockIdx.x * blockDim.x + threadIdx.x;
    if (i >= n4) return;
    int node = i >> 5;  // 32 float4 per row (H=128)
    float nn = nrm[node];
    float4 v = ((const float4*)feat)[i];
    v.x *= nn; v.y *= nn; v.z *= nn; v.w *= nn;
    ((float4*)featn)[i] = v;
}

// ---------------- per-iteration kernels ----------------

// lidx==0: argmax over input logits. one wave per node, lane = class.
__global__ __launch_bounds__(256) void k_pred0(const float* __restrict__ logits,
                                               int* __restrict__ pred, int n) {
    int wid = (blockIdx.x * blockDim.x + threadIdx.x) >> 6;
    int lane = threadIdx.x & 63;
    if (wid >= n) return;
    float v = logits[(size_t)wid * C + lane];
    int idx = lane;
    #pragma unroll
    for (int off = 1; off < 64; off <<= 1) {
        float ov = __shfl_xor(v, off);
        int oi = __shfl_xor(idx, off);
        if (ov > v || (ov == v && oi < idx)) { v = ov; idx = oi; }
    }
    if (lane == 0) pred[wid] = idx;
}

// lidx>0: thread-per-node logits = featn@w + b, pred = argmax.
// featn already carries the norm scaling.
__global__ __launch_bounds__(256) void k_predG(const float* __restrict__ featn,
                                               const float* __restrict__ w_y,
                                               const float* __restrict__ b_y,
                                               int* __restrict__ pred, int n) {
    int node = blockIdx.x * blockDim.x + threadIdx.x;
    bool act = node < n;
    int ld = act ? node : 0;
    const float4* p4 = (const float4*)(featn + (size_t)ld * H);
    float fv[H];
    #pragma unroll
    for (int q = 0; q < H / 4; ++q) {
        float4 t = p4[q];
        fv[q * 4 + 0] = t.x;
        fv[q * 4 + 1] = t.y;
        fv[q * 4 + 2] = t.z;
        fv[q * 4 + 3] = t.w;
    }
    float best = -3.402823466e+38f;
    int bi = 0;
    for (int cb = 0; cb < C / 8; ++cb) {
        float acc[8];
        #pragma unroll
        for (int u = 0; u < 8; ++u) acc[u] = 0.f;
        const float* wp = w_y + cb * 8;
        #pragma unroll
        for (int h = 0; h < H; ++h) {
            #pragma unroll
            for (int u = 0; u < 8; ++u)
                acc[u] = fmaf(fv[h], wp[h * C + u], acc[u]);
        }
        #pragma unroll
        for (int u = 0; u < 8; ++u) {
            float val = acc[u] + b_y[cb * 8 + u];
            int c = cb * 8 + u;
            if (val > best) { best = val; bi = c; }  // strict > keeps first index
        }
    }
    if (act) pred[node] = bi;
}

// f1 (agreement fraction), f2 (histogram entropy), + LN stat sums.
__global__ __launch_bounds__(256) void k_edge(const int* __restrict__ row_ptr,
                                              const int* __restrict__ csr_src,
                                              const int* __restrict__ pred,
                                              const float* __restrict__ degc,
                                              float* __restrict__ f1, float* __restrict__ f2,
                                              double* __restrict__ stats_iter, int n) {
    __shared__ unsigned char hist[256][64];
    __shared__ double red[256];
    int t = threadIdx.x;
    int node = blockIdx.x * 256 + t;
    uint32_t* hp = (uint32_t*)hist[t];
    #pragma unroll
    for (int q = 0; q < 16; ++q) hp[q] = 0u;
    float v1 = 0.f, v2 = 0.f;
    bool act = node < n;
    if (act) {
        int lo = row_ptr[node], hi = row_ptr[node + 1];
        int pc = pred[node];
        int eq = 0;
        for (int j = lo; j < hi; ++j) {
            int p = pred[csr_src[j]];
            eq += (p == pc) ? 1 : 0;
            hist[t][p] += 1;
        }
        float dc = degc[node];
        v1 = (float)eq / dc;
        float s = 0.f;
        #pragma unroll
        for (int c = 0; c < 64; ++c) {
            float cv = (float)hist[t][c] / dc;
            cv = fmaxf(cv, 1e-5f);
            s += cv * logf(cv);
        }
        v2 = -s;
        f1[node] = v1;
        f2[node] = v2;
    }
    double vals[4];
    vals[0] = act ? (double)v1 : 0.0;
    vals[1] = act ? (double)v1 * (double)v1 : 0.0;
    vals[2] = act ? (double)v2 : 0.0;
    vals[3] = act ? (double)v2 * (double)v2 : 0.0;
    for (int q = 0; q < 4; ++q) {
        red[t] = vals[q];
        __syncthreads();
        for (int off = 128; off >= 1; off >>= 1) {
            if (t < off) red[t] += red[t + off];
            __syncthreads();
        }
        if (t == 0) atomicAdd(&stats_iter[q], red[0]);
        __syncthreads();
    }
}

// SpMM on pre-scaled featn + z + residual. One wave per node; lane = 2 dims.
// Writes featn_{l+1} = (z*agg*nr + featn_l)*nr, or feat (no trailing *nr) when last.
__global__ __launch_bounds__(256) void k_spmm(const float* __restrict__ featn,
                                              float* __restrict__ nxt,
                                              const float* __restrict__ nrm,
                                              const int* __restrict__ row_ptr,
                                              const int* __restrict__ csr_src,
                                              const float* __restrict__ f1,
                                              const float* __restrict__ f2,
                                              const double* __restrict__ stats_iter,
                                              const float* __restrict__ tau1,
                                              const float* __restrict__ tau2,
                                              int n, double dN, int last) {
    int wid = (blockIdx.x * blockDim.x + threadIdx.x) >> 6;
    int lane = threadIdx.x & 63;
    if (wid >= n) return;
    int node = __builtin_amdgcn_readfirstlane(wid);

    // z from global-LN(f1), LN(f2) stats
    double S1 = stats_iter[0], Q1 = stats_iter[1];
    double S2 = stats_iter[2], Q2 = stats_iter[3];
    double m1 = S1 / dN, m2 = S2 / dN;
    double rs1 = 1.0 / sqrt(Q1 / dN - m1 * m1 + 1e-5);
    double rs2 = 1.0 / sqrt(Q2 / dN - m2 * m2 + 1e-5);
    float ln1 = (float)(((double)f1[node] - m1) * rs1);
    float ln2 = (float)(((double)f2[node] - m2) * rs2);
    float z1 = 1.f / (1.f + expf(ln1 - tau1[0]));  // sigmoid(-(ln1 - tau1))
    float z2 = 1.f / (1.f + expf(ln2 - tau2[0]));
    float z = z1 * z2;

    float nr = nrm[node];
    int lo = row_ptr[node], hi = row_ptr[node + 1];
    float ax = 0.f, ay = 0.f;
    const float* basep = featn + (size_t)lane * 2;
    int j = lo;
    for (; j + 3 < hi; j += 4) {
        int s0 = csr_src[j];
        int s1 = csr_src[j + 1];
        int s2 = csr_src[j + 2];
        int s3 = csr_src[j + 3];
        const float2 v0 = *(const float2*)(basep + (size_t)s0 * H);
        const float2 v1 = *(const float2*)(basep + (size_t)s1 * H);
        const float2 v2 = *(const float2*)(basep + (size_t)s2 * H);
        const float2 v3 = *(const float2*)(basep + (size_t)s3 * H);
        ax += v0.x; ay += v0.y;
        ax += v1.x; ay += v1.y;
        ax += v2.x; ay += v2.y;
        ax += v3.x; ay += v3.y;
    }
    for (; j < hi; ++j) {
        int s0 = csr_src[j];
        const float2 v0 = *(const float2*)(basep + (size_t)s0 * H);
        ax += v0.x; ay += v0.y;
    }
    const float2 ownn = *(const float2*)(featn + (size_t)node * H + lane * 2);
    float ox = fmaf(z, ax * nr, ownn.x);
    float oy = fmaf(z, ay * nr, ownn.y);
    if (!last) { ox *= nr; oy *= nr; }
    float2 o; o.x = ox; o.y = oy;
    *(float2*)(nxt + (size_t)node * H + lane * 2) = o;
}

// ---------------- host ----------------

extern "C" void kernel_launch(void* const* d_in, const int* in_sizes, int n_in,
                              void* d_out, int out_size, void* d_ws, size_t ws_size,
                              hipStream_t stream) {
    const float* feat   = (const float*)d_in[0];
    const float* logits = (const float*)d_in[1];
    const float* w_y    = (const float*)d_in[2];
    const float* b_y    = (const float*)d_in[3];
    const float* tau1   = (const float*)d_in[4];
    const float* tau2   = (const float*)d_in[5];
    const int*   src    = (const int*)d_in[6];
    const int*   dst    = (const int*)d_in[7];

    const int N = in_sizes[0] / H;
    const int E = in_sizes[6];
    float* out = (float*)d_out;

    char* ws = (char*)d_ws;
    size_t off = 0;
    auto carve = [&](size_t bytes) -> char* {
        char* p = ws + off;
        off = (off + bytes + 255) & ~(size_t)255;
        return p;
    };
    float*  featnA  = (float*)carve((size_t)N * H * sizeof(float));
    float*  featnB  = (float*)carve((size_t)N * H * sizeof(float));
    float*  nrm     = (float*)carve((size_t)N * sizeof(float));
    float*  degc    = (float*)carve((size_t)N * sizeof(float));
    int*    pred    = (int*)  carve((size_t)N * sizeof(int));
    float*  f1      = (float*)carve((size_t)N * sizeof(float));
    float*  f2      = (float*)carve((size_t)N * sizeof(float));
    int*    deg     = (int*)  carve((size_t)N * sizeof(int));
    int*    row_ptr = (int*)  carve((size_t)(N + 1) * sizeof(int));
    int*    row_cur = (int*)  carve((size_t)N * sizeof(int));
    int*    bsum    = (int*)  carve((size_t)1024 * sizeof(int));
    int*    csr_src = (int*)  carve((size_t)E * sizeof(int));
    double* stats   = (double*)carve((size_t)KITER * 8 * sizeof(double));

    const int TB = 256;
    int gN = (N + TB - 1) / TB;   // also nb for the scan
    int gE = (E + TB - 1) / TB;

    k_zero<<<gN, TB, 0, stream>>>(deg, stats, N, KITER * 8);
    k_degcount<<<gE, TB, 0, stream>>>(dst, deg, E);
    k_blocksum<<<gN, TB, 0, stream>>>(deg, bsum, N);
    k_scanb<<<1, 512, 0, stream>>>(bsum, bsum + 512, row_ptr, gN, N);
    k_fill<<<gN, TB, 0, stream>>>(deg, bsum + 512, row_ptr, row_cur, N);
    k_norm<<<gN, TB, 0, stream>>>(deg, degc, nrm, N);
    k_scatter<<<gE, TB, 0, stream>>>(src, dst, row_cur, csr_src, E);
    int n4 = N * (H / 4);
    k_scale<<<(n4 + TB - 1) / TB, TB, 0, stream>>>(feat, nrm, featnA, n4);

    const float* cur = featnA;  // featn_0
    int gWave = (N + 3) / 4;    // wave-per-node kernels: 4 nodes / 256-thread block
    for (int l = 0; l < KITER; ++l) {
        int last = (l == KITER - 1);
        float* nxt = last ? out : ((l % 2 == 0) ? featnB : featnA);
        if (l == 0)
            k_pred0<<<gWave, TB, 0, stream>>>(logits, pred, N);
        else
            k_predG<<<gN, TB, 0, stream>>>(cur, w_y, b_y, pred, N);
        k_edge<<<gN, TB, 0, stream>>>(row_ptr, csr_src, pred, degc, f1, f2,
                                      stats + (size_t)l * 8, N);
        k_spmm<<<gWave, TB, 0, stream>>>(cur, nxt, nrm, row_ptr, csr_src, f1, f2,
                                         stats + (size_t)l * 8, tau1, tau2, N,
                                         (double)N, last);
        cur = nxt;
    }
}

// Round 4
// 2248.247 us; speedup vs baseline: 1.1234x; 1.0200x over previous
//
#include <hip/hip_runtime.h>
#include <cstdint>
#include <cstddef>

#define H 128
#define C 64
#define KITER 10
#define SCHUNK 4096

// ---------------- setup kernels ----------------

__global__ void k_zero(int* __restrict__ deg, double* __restrict__ stats, int n, int nstats) {
    int i = blockIdx.x * blockDim.x + threadIdx.x;
    if (i < n) deg[i] = 0;
    if (i < nstats) stats[i] = 0.0;
}

__global__ void k_degcount(const int* __restrict__ dst, int* __restrict__ deg, int E) {
    int e = blockIdx.x * blockDim.x + threadIdx.x;
    if (e < E) atomicAdd(&deg[dst[e]], 1);
}

// ---- multi-block exclusive scan of deg -> row_ptr/row_cur ----

__global__ __launch_bounds__(256) void k_blocksum(const int* __restrict__ deg,
                                                  int* __restrict__ bsum, int n) {
    __shared__ int red[256];
    int t = threadIdx.x;
    int i = blockIdx.x * 256 + t;
    red[t] = (i < n) ? deg[i] : 0;
    __syncthreads();
    for (int off = 128; off >= 1; off >>= 1) {
        if (t < off) red[t] += red[t + off];
        __syncthreads();
    }
    if (t == 0) bsum[blockIdx.x] = red[0];
}

__global__ __launch_bounds__(512) void k_scanb(const int* __restrict__ bsum,
                                               int* __restrict__ boff,
                                               int* __restrict__ row_ptr, int nb, int n) {
    __shared__ int s[512];
    int t = threadIdx.x;
    int v = (t < nb) ? bsum[t] : 0;
    s[t] = v;
    __syncthreads();
    for (int off = 1; off < 512; off <<= 1) {
        int u = (t >= off) ? s[t - off] : 0;
        __syncthreads();
        s[t] += u;
        __syncthreads();
    }
    if (t < nb) boff[t] = s[t] - v;  // exclusive
    if (t == 511) row_ptr[n] = s[511];
}

__global__ __launch_bounds__(256) void k_fill(const int* __restrict__ deg,
                                              const int* __restrict__ boff,
                                              int* __restrict__ row_ptr,
                                              int* __restrict__ row_cur, int n) {
    __shared__ int s[256];
    int t = threadIdx.x;
    int i = blockIdx.x * 256 + t;
    int d = (i < n) ? deg[i] : 0;
    s[t] = d;
    __syncthreads();
    for (int off = 1; off < 256; off <<= 1) {
        int u = (t >= off) ? s[t - off] : 0;
        __syncthreads();
        s[t] += u;
        __syncthreads();
    }
    if (i < n) {
        int base = boff[blockIdx.x] + s[t] - d;
        row_ptr[i] = base;
        row_cur[i] = base;
    }
}

__global__ void k_norm(const int* __restrict__ deg, float* __restrict__ degc,
                       float* __restrict__ nrm, int n) {
    int i = blockIdx.x * blockDim.x + threadIdx.x;
    if (i < n) {
        int d = deg[i];
        float dc = (float)(d > 1 ? d : 1);
        degc[i] = dc;
        nrm[i] = (float)(1.0 / sqrt((double)dc));  // correctly-rounded dc^-0.5
    }
}

// XCD-sliced scatter: 8 mate-blocks per edge chunk; mate x (blockIdx&7 -> XCD x
// under round-robin dispatch) writes only dst in node-slice x. Keeps each csr
// line resident in ONE XCD L2 until its ~16 entries land -> 1 writeback/line.
__global__ __launch_bounds__(256) void k_scatter8(const int* __restrict__ src,
                                                  const int* __restrict__ dst,
                                                  int* __restrict__ row_cur,
                                                  int* __restrict__ csr_src,
                                                  int E, int slice_sz) {
    int chunk = blockIdx.x >> 3;
    int xcd = blockIdx.x & 7;
    int base = chunk * SCHUNK;
    int lo_node = xcd * slice_sz;
    int hi_node = lo_node + slice_sz;
    #pragma unroll
    for (int r = 0; r < SCHUNK; r += 256) {
        int e = base + r + threadIdx.x;
        if (e < E) {
            int d = dst[e];
            if (d >= lo_node && d < hi_node) {
                int pos = atomicAdd(&row_cur[d], 1);
                csr_src[pos] = src[e];
            }
        }
    }
}

// featn0 = feat * norm (thread per float4)
__global__ __launch_bounds__(256) void k_scale(const float* __restrict__ feat,
                                               const float* __restrict__ nrm,
                                               float* __restrict__ featn, int n4) {
    int i = blockIdx.x * blockDim.x + threadIdx.x;
    if (i >= n4) return;
    int node = i >> 5;  // 32 float4 per row (H=128)
    float nn = nrm[node];
    float4 v = ((const float4*)feat)[i];
    v.x *= nn; v.y *= nn; v.z *= nn; v.w *= nn;
    ((float4*)featn)[i] = v;
}

// ---------------- per-iteration kernels ----------------

__global__ __launch_bounds__(256) void k_pred0(const float* __restrict__ logits,
                                               int* __restrict__ pred, int n) {
    int wid = (blockIdx.x * blockDim.x + threadIdx.x) >> 6;
    int lane = threadIdx.x & 63;
    if (wid >= n) return;
    float v = logits[(size_t)wid * C + lane];
    int idx = lane;
    #pragma unroll
    for (int off = 1; off < 64; off <<= 1) {
        float ov = __shfl_xor(v, off);
        int oi = __shfl_xor(idx, off);
        if (ov > v || (ov == v && oi < idx)) { v = ov; idx = oi; }
    }
    if (lane == 0) pred[wid] = idx;
}

// thread-per-node logits = featn@w + b, pred = argmax (featn carries norm).
__global__ __launch_bounds__(256) void k_predG(const float* __restrict__ featn,
                                               const float* __restrict__ w_y,
                                               const float* __restrict__ b_y,
                                               int* __restrict__ pred, int n) {
    int node = blockIdx.x * blockDim.x + threadIdx.x;
    bool act = node < n;
    int ld = act ? node : 0;
    const float4* p4 = (const float4*)(featn + (size_t)ld * H);
    float fv[H];
    #pragma unroll
    for (int q = 0; q < H / 4; ++q) {
        float4 t = p4[q];
        fv[q * 4 + 0] = t.x;
        fv[q * 4 + 1] = t.y;
        fv[q * 4 + 2] = t.z;
        fv[q * 4 + 3] = t.w;
    }
    float best = -3.402823466e+38f;
    int bi = 0;
    for (int cb = 0; cb < C / 8; ++cb) {
        float acc[8];
        #pragma unroll
        for (int u = 0; u < 8; ++u) acc[u] = 0.f;
        const float* wp = w_y + cb * 8;
        #pragma unroll
        for (int h = 0; h < H; ++h) {
            #pragma unroll
            for (int u = 0; u < 8; ++u)
                acc[u] = fmaf(fv[h], wp[h * C + u], acc[u]);
        }
        #pragma unroll
        for (int u = 0; u < 8; ++u) {
            float val = acc[u] + b_y[cb * 8 + u];
            int c = cb * 8 + u;
            if (val > best) { best = val; bi = c; }  // strict > keeps first index
        }
    }
    if (act) pred[node] = bi;
}

// f1 (agreement fraction), f2 (histogram entropy), + LN stat sums.
__global__ __launch_bounds__(256) void k_edge(const int* __restrict__ row_ptr,
                                              const int* __restrict__ csr_src,
                                              const int* __restrict__ pred,
                                              const float* __restrict__ degc,
                                              float* __restrict__ f1, float* __restrict__ f2,
                                              double* __restrict__ stats_iter, int n) {
    __shared__ unsigned char hist[256][64];
    __shared__ double red[256];
    int t = threadIdx.x;
    int node = blockIdx.x * 256 + t;
    uint32_t* hp = (uint32_t*)hist[t];
    #pragma unroll
    for (int q = 0; q < 16; ++q) hp[q] = 0u;
    float v1 = 0.f, v2 = 0.f;
    bool act = node < n;
    if (act) {
        int lo = row_ptr[node], hi = row_ptr[node + 1];
        int pc = pred[node];
        int eq = 0;
        for (int j = lo; j < hi; ++j) {
            int p = pred[csr_src[j]];
            eq += (p == pc) ? 1 : 0;
            hist[t][p] += 1;
        }
        float dc = degc[node];
        v1 = (float)eq / dc;
        float s = 0.f;
        #pragma unroll
        for (int c = 0; c < 64; ++c) {
            float cv = (float)hist[t][c] / dc;
            cv = fmaxf(cv, 1e-5f);
            s += cv * logf(cv);
        }
        v2 = -s;
        f1[node] = v1;
        f2[node] = v2;
    }
    double vals[4];
    vals[0] = act ? (double)v1 : 0.0;
    vals[1] = act ? (double)v1 * (double)v1 : 0.0;
    vals[2] = act ? (double)v2 : 0.0;
    vals[3] = act ? (double)v2 * (double)v2 : 0.0;
    for (int q = 0; q < 4; ++q) {
        red[t] = vals[q];
        __syncthreads();
        for (int off = 128; off >= 1; off >>= 1) {
            if (t < off) red[t] += red[t + off];
            __syncthreads();
        }
        if (t == 0) atomicAdd(&stats_iter[q], red[0]);
        __syncthreads();
    }
}

// SpMM on pre-scaled featn (f32) + z + residual. One wave per node; lane = 2 dims.
__global__ __launch_bounds__(256) void k_spmm(const float* __restrict__ featn,
                                              float* __restrict__ nxt,
                                              const float* __restrict__ nrm,
                                              const int* __restrict__ row_ptr,
                                              const int* __restrict__ csr_src,
                                              const float* __restrict__ f1,
                                              const float* __restrict__ f2,
                                              const double* __restrict__ stats_iter,
                                              const float* __restrict__ tau1,
                                              const float* __restrict__ tau2,
                                              int n, double dN, int last) {
    int wid = (blockIdx.x * blockDim.x + threadIdx.x) >> 6;
    int lane = threadIdx.x & 63;
    if (wid >= n) return;
    int node = __builtin_amdgcn_readfirstlane(wid);

    // z from global-LN(f1), LN(f2) stats
    double S1 = stats_iter[0], Q1 = stats_iter[1];
    double S2 = stats_iter[2], Q2 = stats_iter[3];
    double m1 = S1 / dN, m2 = S2 / dN;
    double rs1 = 1.0 / sqrt(Q1 / dN - m1 * m1 + 1e-5);
    double rs2 = 1.0 / sqrt(Q2 / dN - m2 * m2 + 1e-5);
    float ln1 = (float)(((double)f1[node] - m1) * rs1);
    float ln2 = (float)(((double)f2[node] - m2) * rs2);
    float z1 = 1.f / (1.f + expf(ln1 - tau1[0]));  // sigmoid(-(ln1 - tau1))
    float z2 = 1.f / (1.f + expf(ln2 - tau2[0]));
    float z = z1 * z2;

    float nr = nrm[node];
    int lo = row_ptr[node], hi = row_ptr[node + 1];
    float ax = 0.f, ay = 0.f;
    const float* basep = featn + (size_t)lane * 2;
    int j = lo;
    for (; j + 3 < hi; j += 4) {
        int s0 = csr_src[j];
        int s1 = csr_src[j + 1];
        int s2 = csr_src[j + 2];
        int s3 = csr_src[j + 3];
        const float2 v0 = *(const float2*)(basep + (size_t)s0 * H);
        const float2 v1 = *(const float2*)(basep + (size_t)s1 * H);
        const float2 v2 = *(const float2*)(basep + (size_t)s2 * H);
        const float2 v3 = *(const float2*)(basep + (size_t)s3 * H);
        ax += v0.x; ay += v0.y;
        ax += v1.x; ay += v1.y;
        ax += v2.x; ay += v2.y;
        ax += v3.x; ay += v3.y;
    }
    for (; j < hi; ++j) {
        int s0 = csr_src[j];
        const float2 v0 = *(const float2*)(basep + (size_t)s0 * H);
        ax += v0.x; ay += v0.y;
    }
    const float2 ownn = *(const float2*)(featn + (size_t)node * H + lane * 2);
    float ox = fmaf(z, ax * nr, ownn.x);
    float oy = fmaf(z, ay * nr, ownn.y);
    if (!last) { ox *= nr; oy *= nr; }  // pre-apply next iter's leading feat*norm
    float2 o; o.x = ox; o.y = oy;
    *(float2*)(nxt + (size_t)node * H + lane * 2) = o;
}

// ---------------- host ----------------

extern "C" void kernel_launch(void* const* d_in, const int* in_sizes, int n_in,
                              void* d_out, int out_size, void* d_ws, size_t ws_size,
                              hipStream_t stream) {
    const float* feat   = (const float*)d_in[0];
    const float* logits = (const float*)d_in[1];
    const float* w_y    = (const float*)d_in[2];
    const float* b_y    = (const float*)d_in[3];
    const float* tau1   = (const float*)d_in[4];
    const float* tau2   = (const float*)d_in[5];
    const int*   src    = (const int*)d_in[6];
    const int*   dst    = (const int*)d_in[7];

    const int N = in_sizes[0] / H;
    const int E = in_sizes[6];
    float* out = (float*)d_out;

    char* ws = (char*)d_ws;
    size_t off = 0;
    auto carve = [&](size_t bytes) -> char* {
        char* p = ws + off;
        off = (off + bytes + 255) & ~(size_t)255;
        return p;
    };
    float*  featnA  = (float*)carve((size_t)N * H * sizeof(float));
    float*  featnB  = (float*)carve((size_t)N * H * sizeof(float));
    float*  nrm     = (float*)carve((size_t)N * sizeof(float));
    float*  degc    = (float*)carve((size_t)N * sizeof(float));
    int*    pred    = (int*)  carve((size_t)N * sizeof(int));
    float*  f1      = (float*)carve((size_t)N * sizeof(float));
    float*  f2      = (float*)carve((size_t)N * sizeof(float));
    int*    deg     = (int*)  carve((size_t)N * sizeof(int));
    int*    row_ptr = (int*)  carve((size_t)(N + 1) * sizeof(int));
    int*    row_cur = (int*)  carve((size_t)N * sizeof(int));
    int*    bsum    = (int*)  carve((size_t)1024 * sizeof(int));
    int*    csr_src = (int*)  carve((size_t)E * sizeof(int));
    double* stats   = (double*)carve((size_t)KITER * 8 * sizeof(double));

    const int TB = 256;
    int gN = (N + TB - 1) / TB;   // also nb for the scan
    int gE = (E + TB - 1) / TB;

    k_zero<<<gN, TB, 0, stream>>>(deg, stats, N, KITER * 8);
    k_degcount<<<gE, TB, 0, stream>>>(dst, deg, E);
    k_blocksum<<<gN, TB, 0, stream>>>(deg, bsum, N);
    k_scanb<<<1, 512, 0, stream>>>(bsum, bsum + 512, row_ptr, gN, N);
    k_fill<<<gN, TB, 0, stream>>>(deg, bsum + 512, row_ptr, row_cur, N);
    k_norm<<<gN, TB, 0, stream>>>(deg, degc, nrm, N);
    int nchunk = (E + SCHUNK - 1) / SCHUNK;
    int slice_sz = (N + 7) / 8;
    k_scatter8<<<nchunk * 8, TB, 0, stream>>>(src, dst, row_cur, csr_src, E, slice_sz);
    int n4 = N * (H / 4);
    k_scale<<<(n4 + TB - 1) / TB, TB, 0, stream>>>(feat, nrm, featnA, n4);

    const float* cur = featnA;  // featn_0
    int gWave = (N + 3) / 4;    // wave-per-node: 4 nodes / 256-thread block
    for (int l = 0; l < KITER; ++l) {
        int last = (l == KITER - 1);
        float* nxt = last ? out : ((l % 2 == 0) ? featnB : featnA);
        if (l == 0)
            k_pred0<<<gWave, TB, 0, stream>>>(logits, pred, N);
        else
            k_predG<<<gN, TB, 0, stream>>>(cur, w_y, b_y, pred, N);
        k_edge<<<gN, TB, 0, stream>>>(row_ptr, csr_src, pred, degc, f1, f2,
                                      stats + (size_t)l * 8, N);
        k_spmm<<<gWave, TB, 0, stream>>>(cur, nxt, nrm, row_ptr, csr_src, f1, f2,
                                         stats + (size_t)l * 8, tau1, tau2, N,
                                         (double)N, last);
        cur = nxt;
    }
}

// Round 5
// 1821.989 us; speedup vs baseline: 1.3863x; 1.2340x over previous
//
#include <hip/hip_runtime.h>
#include <hip/hip_fp16.h>
#include <cstdint>
#include <cstddef>

#define H 128
#define C 64
#define KITER 10
#define SCHUNK 4096

// ---------------- setup kernels ----------------

__global__ void k_zero(int* __restrict__ deg, double* __restrict__ stats, int n, int nstats) {
    int i = blockIdx.x * blockDim.x + threadIdx.x;
    if (i < n) deg[i] = 0;
    if (i < nstats) stats[i] = 0.0;
}

__global__ void k_degcount(const int* __restrict__ dst, int* __restrict__ deg, int E) {
    int e = blockIdx.x * blockDim.x + threadIdx.x;
    if (e < E) atomicAdd(&deg[dst[e]], 1);
}

// ---- multi-block exclusive scan of deg -> row_ptr/row_cur ----

__global__ __launch_bounds__(256) void k_blocksum(const int* __restrict__ deg,
                                                  int* __restrict__ bsum, int n) {
    __shared__ int red[256];
    int t = threadIdx.x;
    int i = blockIdx.x * 256 + t;
    red[t] = (i < n) ? deg[i] : 0;
    __syncthreads();
    for (int off = 128; off >= 1; off >>= 1) {
        if (t < off) red[t] += red[t + off];
        __syncthreads();
    }
    if (t == 0) bsum[blockIdx.x] = red[0];
}

__global__ __launch_bounds__(512) void k_scanb(const int* __restrict__ bsum,
                                               int* __restrict__ boff,
                                               int* __restrict__ row_ptr, int nb, int n) {
    __shared__ int s[512];
    int t = threadIdx.x;
    int v = (t < nb) ? bsum[t] : 0;
    s[t] = v;
    __syncthreads();
    for (int off = 1; off < 512; off <<= 1) {
        int u = (t >= off) ? s[t - off] : 0;
        __syncthreads();
        s[t] += u;
        __syncthreads();
    }
    if (t < nb) boff[t] = s[t] - v;  // exclusive
    if (t == 511) row_ptr[n] = s[511];
}

__global__ __launch_bounds__(256) void k_fill(const int* __restrict__ deg,
                                              const int* __restrict__ boff,
                                              int* __restrict__ row_ptr,
                                              int* __restrict__ row_cur, int n) {
    __shared__ int s[256];
    int t = threadIdx.x;
    int i = blockIdx.x * 256 + t;
    int d = (i < n) ? deg[i] : 0;
    s[t] = d;
    __syncthreads();
    for (int off = 1; off < 256; off <<= 1) {
        int u = (t >= off) ? s[t - off] : 0;
        __syncthreads();
        s[t] += u;
        __syncthreads();
    }
    if (i < n) {
        int base = boff[blockIdx.x] + s[t] - d;
        row_ptr[i] = base;
        row_cur[i] = base;
    }
}

__global__ void k_norm(const int* __restrict__ deg, float* __restrict__ degc,
                       float* __restrict__ nrm, int n) {
    int i = blockIdx.x * blockDim.x + threadIdx.x;
    if (i < n) {
        int d = deg[i];
        float dc = (float)(d > 1 ? d : 1);
        degc[i] = dc;
        nrm[i] = (float)(1.0 / sqrt((double)dc));  // correctly-rounded dc^-0.5
    }
}

// XCD-sliced scatter: 8 mate-blocks per edge chunk; mate x (blockIdx&7 -> XCD x
// under round-robin dispatch) writes only dst in node-slice x. Keeps each csr
// line resident in ONE XCD L2 until its ~16 entries land -> 1 writeback/line.
// (R4 evidence: k_scatter dropped out of top-5; WRITE_SIZE collapse confirmed.)
__global__ __launch_bounds__(256) void k_scatter8(const int* __restrict__ src,
                                                  const int* __restrict__ dst,
                                                  int* __restrict__ row_cur,
                                                  int* __restrict__ csr_src,
                                                  int E, int slice_sz) {
    int chunk = blockIdx.x >> 3;
    int xcd = blockIdx.x & 7;
    int base = chunk * SCHUNK;
    int lo_node = xcd * slice_sz;
    int hi_node = lo_node + slice_sz;
    #pragma unroll
    for (int r = 0; r < SCHUNK; r += 256) {
        int e = base + r + threadIdx.x;
        if (e < E) {
            int d = dst[e];
            if (d >= lo_node && d < hi_node) {
                int pos = atomicAdd(&row_cur[d], 1);
                csr_src[pos] = src[e];
            }
        }
    }
}

__device__ inline uint32_t pack_h2(float x, float y) {
    __half2 h = __floats2half2_rn(x, y);
    return __builtin_bit_cast(uint32_t, h);
}
__device__ inline float2 unpack_h2(uint32_t p) {
    __half2 h = __builtin_bit_cast(__half2, p);
    return __half22float2(h);
}

// featn0 = feat * norm (f32 master) + fp16 mirror. thread per float4.
__global__ __launch_bounds__(256) void k_scale(const float* __restrict__ feat,
                                               const float* __restrict__ nrm,
                                               float* __restrict__ featn,
                                               uint32_t* __restrict__ mir, int n4) {
    int i = blockIdx.x * blockDim.x + threadIdx.x;
    if (i >= n4) return;
    int node = i >> 5;  // 32 float4 per row (H=128)
    float nn = nrm[node];
    float4 v = ((const float4*)feat)[i];
    v.x *= nn; v.y *= nn; v.z *= nn; v.w *= nn;
    ((float4*)featn)[i] = v;
    mir[i * 2]     = pack_h2(v.x, v.y);
    mir[i * 2 + 1] = pack_h2(v.z, v.w);
}

// ---------------- per-iteration kernels ----------------

__global__ __launch_bounds__(256) void k_pred0(const float* __restrict__ logits,
                                               int* __restrict__ pred, int n) {
    int wid = (blockIdx.x * blockDim.x + threadIdx.x) >> 6;
    int lane = threadIdx.x & 63;
    if (wid >= n) return;
    float v = logits[(size_t)wid * C + lane];
    int idx = lane;
    #pragma unroll
    for (int off = 1; off < 64; off <<= 1) {
        float ov = __shfl_xor(v, off);
        int oi = __shfl_xor(idx, off);
        if (ov > v || (ov == v && oi < idx)) { v = ov; idx = oi; }
    }
    if (lane == 0) pred[wid] = idx;
}

// thread-per-node logits = featn@w + b, pred = argmax (featn f32 master).
__global__ __launch_bounds__(256) void k_predG(const float* __restrict__ featn,
                                               const float* __restrict__ w_y,
                                               const float* __restrict__ b_y,
                                               int* __restrict__ pred, int n) {
    int node = blockIdx.x * blockDim.x + threadIdx.x;
    bool act = node < n;
    int ld = act ? node : 0;
    const float4* p4 = (const float4*)(featn + (size_t)ld * H);
    float fv[H];
    #pragma unroll
    for (int q = 0; q < H / 4; ++q) {
        float4 t = p4[q];
        fv[q * 4 + 0] = t.x;
        fv[q * 4 + 1] = t.y;
        fv[q * 4 + 2] = t.z;
        fv[q * 4 + 3] = t.w;
    }
    float best = -3.402823466e+38f;
    int bi = 0;
    for (int cb = 0; cb < C / 8; ++cb) {
        float acc[8];
        #pragma unroll
        for (int u = 0; u < 8; ++u) acc[u] = 0.f;
        const float* wp = w_y + cb * 8;
        #pragma unroll
        for (int h = 0; h < H; ++h) {
            #pragma unroll
            for (int u = 0; u < 8; ++u)
                acc[u] = fmaf(fv[h], wp[h * C + u], acc[u]);
        }
        #pragma unroll
        for (int u = 0; u < 8; ++u) {
            float val = acc[u] + b_y[cb * 8 + u];
            int c = cb * 8 + u;
            if (val > best) { best = val; bi = c; }  // strict > keeps first index
        }
    }
    if (act) pred[node] = bi;
}

// f1 (agreement fraction), f2 (histogram entropy), + LN stat sums.
__global__ __launch_bounds__(256) void k_edge(const int* __restrict__ row_ptr,
                                              const int* __restrict__ csr_src,
                                              const int* __restrict__ pred,
                                              const float* __restrict__ degc,
                                              float* __restrict__ f1, float* __restrict__ f2,
                                              double* __restrict__ stats_iter, int n) {
    __shared__ unsigned char hist[256][64];
    __shared__ double red[256];
    int t = threadIdx.x;
    int node = blockIdx.x * 256 + t;
    uint32_t* hp = (uint32_t*)hist[t];
    #pragma unroll
    for (int q = 0; q < 16; ++q) hp[q] = 0u;
    float v1 = 0.f, v2 = 0.f;
    bool act = node < n;
    if (act) {
        int lo = row_ptr[node], hi = row_ptr[node + 1];
        int pc = pred[node];
        int eq = 0;
        for (int j = lo; j < hi; ++j) {
            int p = pred[csr_src[j]];
            eq += (p == pc) ? 1 : 0;
            hist[t][p] += 1;
        }
        float dc = degc[node];
        v1 = (float)eq / dc;
        float s = 0.f;
        #pragma unroll
        for (int c = 0; c < 64; ++c) {
            float cv = (float)hist[t][c] / dc;
            cv = fmaxf(cv, 1e-5f);
            s += cv * logf(cv);
        }
        v2 = -s;
        f1[node] = v1;
        f2[node] = v2;
    }
    double vals[4];
    vals[0] = act ? (double)v1 : 0.0;
    vals[1] = act ? (double)v1 * (double)v1 : 0.0;
    vals[2] = act ? (double)v2 : 0.0;
    vals[3] = act ? (double)v2 * (double)v2 : 0.0;
    for (int q = 0; q < 4; ++q) {
        red[t] = vals[q];
        __syncthreads();
        for (int off = 128; off >= 1; off >>= 1) {
            if (t < off) red[t] += red[t + off];
            __syncthreads();
        }
        if (t == 0) atomicAdd(&stats_iter[q], red[0]);
        __syncthreads();
    }
}

// SpMM gathering from fp16 mirror (half the bytes; one dword/lane/neighbor),
// f32 accumulate, + z + residual on the f32 master. One wave per node.
__global__ __launch_bounds__(256) void k_spmm(const float* __restrict__ featn,
                                              const uint32_t* __restrict__ mir_cur,
                                              float* __restrict__ nxt,
                                              uint32_t* __restrict__ mir_nxt,
                                              const float* __restrict__ nrm,
                                              const int* __restrict__ row_ptr,
                                              const int* __restrict__ csr_src,
                                              const float* __restrict__ f1,
                                              const float* __restrict__ f2,
                                              const double* __restrict__ stats_iter,
                                              const float* __restrict__ tau1,
                                              const float* __restrict__ tau2,
                                              int n, double dN, int last) {
    int wid = (blockIdx.x * blockDim.x + threadIdx.x) >> 6;
    int lane = threadIdx.x & 63;
    if (wid >= n) return;
    int node = __builtin_amdgcn_readfirstlane(wid);

    // z from global-LN(f1), LN(f2) stats
    double S1 = stats_iter[0], Q1 = stats_iter[1];
    double S2 = stats_iter[2], Q2 = stats_iter[3];
    double m1 = S1 / dN, m2 = S2 / dN;
    double rs1 = 1.0 / sqrt(Q1 / dN - m1 * m1 + 1e-5);
    double rs2 = 1.0 / sqrt(Q2 / dN - m2 * m2 + 1e-5);
    float ln1 = (float)(((double)f1[node] - m1) * rs1);
    float ln2 = (float)(((double)f2[node] - m2) * rs2);
    float z1 = 1.f / (1.f + expf(ln1 - tau1[0]));  // sigmoid(-(ln1 - tau1))
    float z2 = 1.f / (1.f + expf(ln2 - tau2[0]));
    float z = z1 * z2;

    float nr = nrm[node];
    int lo = row_ptr[node], hi = row_ptr[node + 1];
    float ax = 0.f, ay = 0.f;
    const uint32_t* basep = mir_cur + lane;  // row stride = 64 dwords (128 halves)
    int j = lo;
    for (; j + 3 < hi; j += 4) {
        int s0 = csr_src[j];
        int s1 = csr_src[j + 1];
        int s2 = csr_src[j + 2];
        int s3 = csr_src[j + 3];
        uint32_t p0 = basep[(size_t)s0 * 64];
        uint32_t p1 = basep[(size_t)s1 * 64];
        uint32_t p2 = basep[(size_t)s2 * 64];
        uint32_t p3 = basep[(size_t)s3 * 64];
        float2 f0 = unpack_h2(p0); ax += f0.x; ay += f0.y;
        float2 g1 = unpack_h2(p1); ax += g1.x; ay += g1.y;
        float2 g2 = unpack_h2(p2); ax += g2.x; ay += g2.y;
        float2 g3 = unpack_h2(p3); ax += g3.x; ay += g3.y;
    }
    for (; j < hi; ++j) {
        int s0 = csr_src[j];
        float2 f0 = unpack_h2(basep[(size_t)s0 * 64]);
        ax += f0.x; ay += f0.y;
    }
    const float2 ownn = *(const float2*)(featn + (size_t)node * H + lane * 2);
    float ox = fmaf(z, ax * nr, ownn.x);
    float oy = fmaf(z, ay * nr, ownn.y);
    if (!last) {
        ox *= nr; oy *= nr;  // pre-apply next iter's leading feat*norm
        mir_nxt[(size_t)node * 64 + lane] = pack_h2(ox, oy);
    }
    float2 o; o.x = ox; o.y = oy;
    *(float2*)(nxt + (size_t)node * H + lane * 2) = o;
}

// ---------------- host ----------------

extern "C" void kernel_launch(void* const* d_in, const int* in_sizes, int n_in,
                              void* d_out, int out_size, void* d_ws, size_t ws_size,
                              hipStream_t stream) {
    const float* feat   = (const float*)d_in[0];
    const float* logits = (const float*)d_in[1];
    const float* w_y    = (const float*)d_in[2];
    const float* b_y    = (const float*)d_in[3];
    const float* tau1   = (const float*)d_in[4];
    const float* tau2   = (const float*)d_in[5];
    const int*   src    = (const int*)d_in[6];
    const int*   dst    = (const int*)d_in[7];

    const int N = in_sizes[0] / H;
    const int E = in_sizes[6];
    float* out = (float*)d_out;

    char* ws = (char*)d_ws;
    size_t off = 0;
    auto carve = [&](size_t bytes) -> char* {
        char* p = ws + off;
        off = (off + bytes + 255) & ~(size_t)255;
        return p;
    };
    float*    featnA  = (float*)carve((size_t)N * H * sizeof(float));
    float*    featnB  = (float*)carve((size_t)N * H * sizeof(float));
    uint32_t* mirA    = (uint32_t*)carve((size_t)N * (H / 2) * sizeof(uint32_t));
    uint32_t* mirB    = (uint32_t*)carve((size_t)N * (H / 2) * sizeof(uint32_t));
    float*    nrm     = (float*)carve((size_t)N * sizeof(float));
    float*    degc    = (float*)carve((size_t)N * sizeof(float));
    int*      pred    = (int*)  carve((size_t)N * sizeof(int));
    float*    f1      = (float*)carve((size_t)N * sizeof(float));
    float*    f2      = (float*)carve((size_t)N * sizeof(float));
    int*      deg     = (int*)  carve((size_t)N * sizeof(int));
    int*      row_ptr = (int*)  carve((size_t)(N + 1) * sizeof(int));
    int*      row_cur = (int*)  carve((size_t)N * sizeof(int));
    int*      bsum    = (int*)  carve((size_t)1024 * sizeof(int));
    int*      csr_src = (int*)  carve((size_t)E * sizeof(int));
    double*   stats   = (double*)carve((size_t)KITER * 8 * sizeof(double));

    const int TB = 256;
    int gN = (N + TB - 1) / TB;   // also nb for the scan
    int gE = (E + TB - 1) / TB;

    k_zero<<<gN, TB, 0, stream>>>(deg, stats, N, KITER * 8);
    k_degcount<<<gE, TB, 0, stream>>>(dst, deg, E);
    k_blocksum<<<gN, TB, 0, stream>>>(deg, bsum, N);
    k_scanb<<<1, 512, 0, stream>>>(bsum, bsum + 512, row_ptr, gN, N);
    k_fill<<<gN, TB, 0, stream>>>(deg, bsum + 512, row_ptr, row_cur, N);
    k_norm<<<gN, TB, 0, stream>>>(deg, degc, nrm, N);
    int nchunk = (E + SCHUNK - 1) / SCHUNK;
    int slice_sz = (N + 7) / 8;
    k_scatter8<<<nchunk * 8, TB, 0, stream>>>(src, dst, row_cur, csr_src, E, slice_sz);
    int n4 = N * (H / 4);
    k_scale<<<(n4 + TB - 1) / TB, TB, 0, stream>>>(feat, nrm, featnA, mirA, n4);

    const float* cur = featnA;     // featn_0 (f32 master)
    const uint32_t* mcur = mirA;   // fp16 mirror of cur
    int gWave = (N + 3) / 4;       // wave-per-node: 4 nodes / 256-thread block
    for (int l = 0; l < KITER; ++l) {
        int last = (l == KITER - 1);
        float* nxt = last ? out : ((l % 2 == 0) ? featnB : featnA);
        uint32_t* mnxt = (l % 2 == 0) ? mirB : mirA;  // unused when last
        if (l == 0)
            k_pred0<<<gWave, TB, 0, stream>>>(logits, pred, N);
        else
            k_predG<<<gN, TB, 0, stream>>>(cur, w_y, b_y, pred, N);
        k_edge<<<gN, TB, 0, stream>>>(row_ptr, csr_src, pred, degc, f1, f2,
                                      stats + (size_t)l * 8, N);
        k_spmm<<<gWave, TB, 0, stream>>>(cur, mcur, nxt, mnxt, nrm, row_ptr, csr_src,
                                         f1, f2, stats + (size_t)l * 8, tau1, tau2,
                                         N, (double)N, last);
        cur = nxt;
        mcur = mnxt;
    }
}